// Round 4
// baseline (2301.927 us; speedup 1.0000x reference)
//
#include <hip/hip_runtime.h>
#include <math.h>

#define NB 512
#define SS 128
#define DD 128
#define NH 8
#define DKK 16
#define NSTEP 126

// ---------------- precompute: wtp/wmp/plcq projections (f64 inner, f32 out) ----
__global__ __launch_bounds__(128) void proj_kernel(
    const float* __restrict__ vtmax, const float* __restrict__ vm,
    const float* __restrict__ wplc, const float* __restrict__ Wupd,
    float* __restrict__ wtp, float* __restrict__ wmp, float* __restrict__ plcq)
{
  int d = threadIdx.x;
  double a = 0.0, b = 0.0, c = 0.0;
  for (int k = 0; k < DD; k++) {
    a += (double)vtmax[k] * (double)Wupd[(size_t)(DD + k) * DD + d];
    b += (double)vm[k]    * (double)Wupd[(size_t)(2 * DD + k) * DD + d];
    c += (double)wplc[k]  * (double)Wupd[(size_t)k * DD + d];
  }
  wtp[d] = (float)a; wmp[d] = (float)b; plcq[d] = (float)c;
}

// ---------------- precompute: h_hat = mean(enc,1) @ W_ctx (f64 inner, f32 out) ----
__global__ __launch_bounds__(128) void hhat_kernel(
    const float* __restrict__ enc, const float* __restrict__ Wctx,
    float* __restrict__ hh)
{
  __shared__ double mean[DD];
  int b = blockIdx.x, d = threadIdx.x;
  double s = 0.0;
  for (int j = 0; j < SS; j++) s += (double)enc[((size_t)b * SS + j) * DD + d];
  mean[d] = s * (1.0 / 128.0);
  __syncthreads();
  double a = 0.0;
  for (int k = 0; k < DD; k++) a += mean[k] * (double)Wctx[(size_t)k * DD + d];
  hh[(size_t)b * DD + d] = (float)a;
}

// ---- precompute GEMM (f64 accumulate, f32 out): C = A(65536x128) @ B(128 x ncols) ----
__global__ __launch_bounds__(256) void gemm64(
    const float* __restrict__ A, const float* __restrict__ Bm, int ldb,
    float* __restrict__ C, int ldc)
{
  __shared__ float As[64][132];
  __shared__ float Bs[64][68];
  const int r0 = blockIdx.x * 64;
  const int c0 = blockIdx.y * 64;
  const int tid = threadIdx.x;
  #pragma unroll
  for (int i = 0; i < 8; i++) {
    int idx = tid + 256 * i;
    int rr = idx >> 5;
    int cc = (idx & 31) << 2;
    *(float4*)&As[rr][cc] = *(const float4*)&A[(size_t)(r0 + rr) * DD + cc];
  }
  const int trow = (tid >> 4) << 2;
  const int tcol = (tid & 15) << 2;
  double acc[4][4] = {};
  for (int kh = 0; kh < 2; kh++) {
    __syncthreads();
    #pragma unroll
    for (int i = 0; i < 4; i++) {
      int idx = tid + 256 * i;
      int rr = idx >> 4;
      int cc = (idx & 15) << 2;
      *(float4*)&Bs[rr][cc] = *(const float4*)&Bm[(size_t)(kh * 64 + rr) * ldb + c0 + cc];
    }
    __syncthreads();
    #pragma unroll 2
    for (int k2 = 0; k2 < 64; k2++) {
      int k = kh * 64 + k2;
      double a0 = (double)As[trow][k],     a1 = (double)As[trow + 1][k],
             a2 = (double)As[trow + 2][k], a3 = (double)As[trow + 3][k];
      float4 b4 = *(const float4*)&Bs[k2][tcol];
      double bx = (double)b4.x, by = (double)b4.y, bz = (double)b4.z, bw = (double)b4.w;
      acc[0][0] += a0 * bx; acc[0][1] += a0 * by; acc[0][2] += a0 * bz; acc[0][3] += a0 * bw;
      acc[1][0] += a1 * bx; acc[1][1] += a1 * by; acc[1][2] += a1 * bz; acc[1][3] += a1 * bw;
      acc[2][0] += a2 * bx; acc[2][1] += a2 * by; acc[2][2] += a2 * bz; acc[2][3] += a2 * bw;
      acc[3][0] += a3 * bx; acc[3][1] += a3 * by; acc[3][2] += a3 * bz; acc[3][3] += a3 * bw;
    }
  }
  #pragma unroll
  for (int i = 0; i < 4; i++) {
    float* cp = &C[(size_t)(r0 + trow + i) * ldc + c0 + tcol];
    cp[0] = (float)acc[i][0]; cp[1] = (float)acc[i][1];
    cp[2] = (float)acc[i][2]; cp[3] = (float)acc[i][3];
  }
}

// ---------------- sequential decoder: one block per batch element ----------------
// Value pipeline: f64 inner dots, f32 stage-rounding at every reference tensor.
// Decision pipeline: exact-f32 state machine (__f*_rn) + f32 log_softmax
// quantization emulation (y = fl32(fl32(l - max) - L), L in lse's binade).
template<bool USE_ENCU>
__global__ __launch_bounds__(256) void decoder_kernel(
    const float* __restrict__ loc, const float* __restrict__ scores,
    const float* __restrict__ Tmax, const int* __restrict__ m_in,
    const float* __restrict__ Wout, const float* __restrict__ Wupd,
    const float* __restrict__ enc,
    const float* __restrict__ kvl, const float* __restrict__ encU,
    const float* __restrict__ hhat,
    const float* __restrict__ wtp, const float* __restrict__ wmp,
    const float* __restrict__ plcq, float* __restrict__ out)
{
  const int b = blockIdx.x;
  const int tid = threadIdx.x;
  const int wv = tid >> 6, ln = tid & 63;

  __shared__ float lx[SS], lyv[SS], d2dep[SS], sc[SS];
  __shared__ float qv[DD];
  __shared__ float comp[NH][SS];        // compat -> attn (f32)
  __shared__ double hpart[2][DD];
  __shared__ float headsv[DD];
  __shared__ float gl[DD];
  __shared__ float lg[SS];              // masked logits (f32)
  __shared__ float shv[SS];             // shifted = fl32(l - max)
  __shared__ float encrow[DD];
  __shared__ int maskv[SS];
  __shared__ float redf[4];
  __shared__ double redd[4];
  __shared__ float redy[2]; __shared__ int redyi[2];
  __shared__ int redi[4];
  __shared__ int bc_city;
  __shared__ float s_Tm, s_T0, s_total;
  __shared__ double s_logp;
  __shared__ int s_last, s_mm, s_start, s_isv, s_startA;

  if (tid < SS) {
    lx[tid]  = loc[((size_t)b * SS + tid) * 2];
    lyv[tid] = loc[((size_t)b * SS + tid) * 2 + 1];
    sc[tid]  = scores[(size_t)b * SS + tid];
    maskv[tid] = (tid < 2) ? 1 : 0;
  }
  if (tid == 0) {
    s_Tm = Tmax[b]; s_T0 = Tmax[b]; s_mm = m_in[b];
    s_start = 1; s_last = 0; s_total = 0.f; s_logp = 0.0;
  }
  __syncthreads();
  if (tid < SS) {
    float dx = __fsub_rn(lx[tid], lx[0]), dy = __fsub_rn(lyv[tid], lyv[0]);
    d2dep[tid] = __fsqrt_rn(__fadd_rn(__fadd_rn(__fmul_rn(dx, dx), __fmul_rn(dy, dy)), 1e-12f));
  }
  float hh_r = 0.f, wtp_r = 0.f, wmp_r = 0.f, plcq_r = 0.f;
  if (tid < DD) {
    hh_r = hhat[(size_t)b * DD + tid];
    wtp_r = wtp[tid]; wmp_r = wmp[tid]; plcq_r = plcq[tid];
  }

  for (int t = 0; t < NSTEP; t++) {
    __syncthreads();                       // state from prev step visible
    if (!USE_ENCU) {
      if (t > 0 && tid < DD)
        encrow[tid] = enc[((size_t)b * SS + s_last) * DD + tid];
      __syncthreads();
    }
    // ---- query (f64 inner, f32 out) ----
    if (tid < DD) {
      double acc = (double)hh_r + (double)s_Tm * (double)wtp_r + (double)s_mm * (double)wmp_r;
      if (t == 0) {
        acc += (double)plcq_r;
      } else if (USE_ENCU) {
        acc += (double)encU[((size_t)b * SS + s_last) * DD + tid];
      } else {
        double s0 = 0.0;
        for (int k = 0; k < DD; k++) s0 += (double)encrow[k] * (double)Wupd[(size_t)k * DD + tid];
        acc += s0;
      }
      qv[tid] = (float)acc;
    }
    __syncthreads();
    // ---- compat = fl32(q . gK) * 0.25, masked ----
    #pragma unroll
    for (int i = 0; i < 4; i++) {
      int p = tid + 256 * i;
      int h = p >> 7, s = p & 127;
      const float* kp = kvl + ((size_t)(b * SS + s)) * 384 + h * DKK;
      const float* qh = qv + h * DKK;
      double c = 0.0;
      #pragma unroll
      for (int j = 0; j < 16; j++) c += (double)kp[j] * (double)qh[j];
      comp[h][s] = maskv[s] ? -INFINITY : __fmul_rn((float)c, 0.25f);
    }
    __syncthreads();
    // ---- softmax per head: f32 max, f32 exp, f64 sum, f32 divide -> attn ----
    #pragma unroll
    for (int hh2 = 0; hh2 < 2; hh2++) {
      int h = wv * 2 + hh2;
      float a0 = comp[h][ln], a1 = comp[h][ln + 64];
      float mx = fmaxf(a0, a1);
      #pragma unroll
      for (int off = 32; off > 0; off >>= 1) mx = fmaxf(mx, __shfl_xor(mx, off));
      float e0 = expf(__fsub_rn(a0, mx)), e1 = expf(__fsub_rn(a1, mx));
      double sm = (double)e0 + (double)e1;
      #pragma unroll
      for (int off = 32; off > 0; off >>= 1) sm += __shfl_xor(sm, off);
      float sumf = (float)sm;
      comp[h][ln]      = __fdiv_rn(e0, sumf);
      comp[h][ln + 64] = __fdiv_rn(e1, sumf);
    }
    __syncthreads();
    // ---- heads = attn . gV (f64 inner) ----
    {
      int di = tid & 15, h = (tid >> 4) & 7, p = tid >> 7;
      const float* vp = kvl + (size_t)b * SS * 384 + 128 + h * DKK + di;
      double acc = 0.0;
      int sbase = p * 64;
      #pragma unroll 8
      for (int s2 = 0; s2 < 64; s2++)
        acc += (double)comp[h][sbase + s2] * (double)vp[(size_t)(sbase + s2) * 384];
      hpart[p][tid & 127] = acc;
    }
    __syncthreads();
    if (tid < DD) headsv[tid] = (float)(hpart[0][tid] + hpart[1][tid]);
    __syncthreads();
    // ---- glimpse = fl32(heads @ W_out) ----
    if (tid < DD) {
      double a = 0.0;
      #pragma unroll 8
      for (int k = 0; k < DD; k++) a += (double)headsv[k] * (double)Wout[(size_t)k * DD + tid];
      gl[tid] = (float)a;
    }
    __syncthreads();
    // ---- logits: fl32(dot), f32 div, f32 tanh*10, masked ----
    if (tid < SS) {
      const float* lk = kvl + ((size_t)(b * SS + tid)) * 384 + 256;
      double a = 0.0;
      #pragma unroll 8
      for (int k = 0; k < DD; k++) a += (double)lk[k] * (double)gl[k];
      float dotf = (float)a;
      float z = __fdiv_rn(dotf, 11.313708498984761f);
      float l = __fmul_rn(tanhf(z), 10.0f);
      lg[tid] = maskv[tid] ? -INFINITY : l;
    }
    __syncthreads();
    // ---- max over 128 (f32) ----
    if (tid < 128) {
      float mv = lg[tid];
      #pragma unroll
      for (int off = 32; off > 0; off >>= 1) mv = fmaxf(mv, __shfl_xor(mv, off));
      if (ln == 0) redf[wv] = mv;
    }
    __syncthreads();
    // ---- quantized argmax: y = fl32(fl32(l - max) - L), L in lse's binade ----
    float Lq = (float)log((double)(NSTEP - t));   // n_t = 126 - t unmasked
    if (tid < 128) {
      float mx128 = fmaxf(redf[0], redf[1]);
      float sh = __fsub_rn(lg[tid], mx128);
      shv[tid] = sh;
      float yv = __fsub_rn(sh, Lq); int yi = tid;
      #pragma unroll
      for (int off = 32; off > 0; off >>= 1) {
        float ov = __shfl_xor(yv, off); int oi = __shfl_xor(yi, off);
        if (ov > yv || (ov == yv && oi < yi)) { yv = ov; yi = oi; }
      }
      if (ln == 0) { redy[wv] = yv; redyi[wv] = yi; }
      double e = exp((double)sh);
      #pragma unroll
      for (int off = 32; off > 0; off >>= 1) e += __shfl_xor(e, off);
      if (ln == 0) redd[wv] = e;
    }
    __syncthreads();
    // ---- pick city + state update part 1 (thread 0, exact f32 state) ----
    if (tid == 0) {
      float yv = redy[0]; int yi = redyi[0];
      if (redy[1] > yv || (redy[1] == yv && redyi[1] < yi)) { yv = redy[1]; yi = redyi[1]; }
      bc_city = yi;
      double sumexp = redd[0] + redd[1];
      s_logp += (double)shv[yi] - log(sumexp);
      int city = yi;
      float dx = __fsub_rn(lx[s_last], lx[city]), dy = __fsub_rn(lyv[s_last], lyv[city]);
      float d_lc = __fsqrt_rn(__fadd_rn(__fadd_rn(__fmul_rn(dx, dx), __fmul_rn(dy, dy)), 1e-12f));
      float d_cd = d2dep[city];
      if (s_start) d_lc = d_cd;
      int isv = (__fadd_rn(d_lc, d_cd) <= s_Tm) ? 1 : 0;
      if (isv) { s_Tm = __fsub_rn(s_Tm, d_lc); s_total = __fadd_rn(s_total, sc[city]); }
      s_isv = isv;
      s_startA = (isv && s_start) ? 0 : s_start;
      out[1024 + (size_t)b * NSTEP + t] = (float)city;
    }
    __syncthreads();
    // ---- all-greater check (old last, old mask, new Tm; exact f32) ----
    if (tid < 128) {
      int g = 1;
      if (tid >= 1) {
        float dx = __fsub_rn(lx[s_last], lx[tid]), dy = __fsub_rn(lyv[s_last], lyv[tid]);
        float dlo = __fsqrt_rn(__fadd_rn(__fadd_rn(__fmul_rn(dx, dx), __fmul_rn(dy, dy)), 1e-12f));
        g = ((__fadd_rn(dlo, d2dep[tid]) > s_Tm) || maskv[tid]) ? 1 : 0;
      }
      int aw = __all(g);
      if (ln == 0) redi[wv] = aw;
    }
    __syncthreads();
    // ---- state update part 2 (thread 0) ----
    if (tid == 0) {
      int all_g = redi[0] && redi[1];
      int dbl = (all_g && (s_mm - 1 > 0)) ? 1 : 0;
      if (dbl) { s_mm -= 1; s_Tm = s_T0; }
      s_start = (s_startA || dbl) ? 1 : 0;
      if (s_isv) s_last = bc_city;
      maskv[bc_city] = 1;
    }
  }
  __syncthreads();
  if (tid == 0) {
    out[b] = (float)s_logp;
    out[512 + b] = s_total;
  }
}

extern "C" void kernel_launch(void* const* d_in, const int* in_sizes, int n_in,
                              void* d_out, int out_size, void* d_ws, size_t ws_size,
                              hipStream_t stream) {
  const float* enc    = (const float*)d_in[0];
  const float* loc    = (const float*)d_in[1];
  const float* scores = (const float*)d_in[2];
  const float* Tmax   = (const float*)d_in[3];
  const int*   m_in   = (const int*)d_in[4];
  const float* W_ctx  = (const float*)d_in[5];
  const float* W_upd  = (const float*)d_in[6];
  const float* W_nodes= (const float*)d_in[7];
  const float* W_out  = (const float*)d_in[8];
  const float* vtmax  = (const float*)d_in[9];
  const float* vm     = (const float*)d_in[10];
  const float* Wplc   = (const float*)d_in[11];
  float* out = (float*)d_out;
  float* ws  = (float*)d_ws;

  float* kvl  = ws;                        // 25165824 floats (100.7 MB)
  float* hhat = kvl + 25165824;            // 65536
  float* wtp  = hhat + 65536;              // 128
  float* wmp  = wtp + 128;                 // 128
  float* plcq = wmp + 128;                 // 128
  float* encU = plcq + 128;                // 8388608 floats (33.6 MB), optional

  const size_t need_base = (size_t)(25165824 + 65536 + 384) * 4;
  const size_t need_full = need_base + (size_t)8388608 * 4;
  const bool use_encu = ws_size >= need_full;

  proj_kernel<<<dim3(1), dim3(128), 0, stream>>>(vtmax, vm, Wplc, W_upd, wtp, wmp, plcq);
  hhat_kernel<<<dim3(NB), dim3(128), 0, stream>>>(enc, W_ctx, hhat);
  gemm64<<<dim3(1024, 6), dim3(256), 0, stream>>>(enc, W_nodes, 384, kvl, 384);
  if (use_encu) {
    gemm64<<<dim3(1024, 2), dim3(256), 0, stream>>>(enc, W_upd, 128, encU, 128);
    decoder_kernel<true><<<dim3(NB), dim3(256), 0, stream>>>(loc, scores, Tmax, m_in, W_out, W_upd, enc,
                                                             kvl, encU, hhat, wtp, wmp, plcq, out);
  } else {
    decoder_kernel<false><<<dim3(NB), dim3(256), 0, stream>>>(loc, scores, Tmax, m_in, W_out, W_upd, enc,
                                                              kvl, (const float*)nullptr, hhat, wtp, wmp, plcq, out);
  }
}